// Round 13
// baseline (663.914 us; speedup 1.0000x reference)
//
#include <hip/hip_runtime.h>
#include <cstdint>

#define M_DIM 8192
#define K_DIM 4096
#define N_DIM 12288
#define KT 64  // K-tiles of BK=64 int8 (64 B per row)

using i32x4 = __attribute__((ext_vector_type(4))) int;

__device__ inline void gload_lds16(const void* g, void* l) {
    __builtin_amdgcn_global_load_lds(
        (const __attribute__((address_space(1))) void*)g,
        (__attribute__((address_space(3))) void*)l,
        16, 0, 0);
}

// ---------------- fused: per-row quant (blocks 0..M-1) + weight repack ----------------
__global__ __launch_bounds__(256) void quant_pack(const float* __restrict__ x,
                                                  const int* __restrict__ w32,
                                                  int8_t* __restrict__ qa,
                                                  float* __restrict__ ascale,
                                                  int8_t* __restrict__ wq) {
    const int t = threadIdx.x;
    if (blockIdx.x < M_DIM) {
        const int row = blockIdx.x;
        const float4* xr = (const float4*)(x + (size_t)row * K_DIM);
        float4 v[4];
        float amax = 0.0f;
#pragma unroll
        for (int c = 0; c < 4; ++c) {
            v[c] = xr[t + 256 * c];
            amax = fmaxf(amax, fmaxf(fmaxf(fabsf(v[c].x), fabsf(v[c].y)),
                                     fmaxf(fabsf(v[c].z), fabsf(v[c].w))));
        }
#pragma unroll
        for (int off = 32; off > 0; off >>= 1)
            amax = fmaxf(amax, __shfl_xor(amax, off));
        __shared__ float smax[4];
        if ((t & 63) == 0) smax[t >> 6] = amax;
        __syncthreads();
        amax = fmaxf(fmaxf(smax[0], smax[1]), fmaxf(smax[2], smax[3]));
        const float sc = amax * (1.0f / 127.0f);
        const float inv = (amax > 0.0f) ? (127.0f / amax) : 0.0f;
        if (t == 0) ascale[row] = sc;

        int* q32 = (int*)(qa + (size_t)row * K_DIM);
#pragma unroll
        for (int c = 0; c < 4; ++c) {
            int q0 = (int)rintf(v[c].x * inv);
            int q1 = (int)rintf(v[c].y * inv);
            int q2 = (int)rintf(v[c].z * inv);
            int q3 = (int)rintf(v[c].w * inv);
            q0 = min(127, max(-128, q0));
            q1 = min(127, max(-128, q1));
            q2 = min(127, max(-128, q2));
            q3 = min(127, max(-128, q3));
            q32[t + 256 * c] = (q0 & 255) | ((q1 & 255) << 8) | ((q2 & 255) << 16) | (q3 << 24);
        }
    } else {
        const int pb = blockIdx.x - M_DIM;  // 0..2047
        const size_t total4 = (size_t)N_DIM * K_DIM / 4;
        const size_t stride = (size_t)2048 * 256;
        int* out32 = (int*)wq;
        for (size_t i = (size_t)pb * 256 + t; i < total4; i += stride) {
            const int4 v = ((const int4*)w32)[i];
            out32[i] = (v.x & 255) | ((v.y & 255) << 8) | ((v.z & 255) << 16) | (v.w << 24);
        }
    }
}

// ---- int8 GEMM: 128x128 tile, 4 waves, ring-2 LDS (32 KB) -> 3 blocks/CU,
// ---- counted vmcnt(4), raw barriers. Independent blocks cover each other's stalls.
__global__ __launch_bounds__(256, 3) void gemm_i8(const int8_t* __restrict__ qa,
                                                  const int8_t* __restrict__ wq,
                                                  const float* __restrict__ ascale,
                                                  const float* __restrict__ wscale,
                                                  const float* __restrict__ bias,
                                                  float* __restrict__ out) {
    __shared__ int8_t lds[2][2][8192];  // [slot][A,B][128 rows x 64 B] = 32 KiB

    const int t = threadIdx.x;
    const int lane = t & 63;
    const int wave = t >> 6;       // 0..3
    const int wm = wave >> 1;      // 0..1 -> 64 rows of A
    const int wn = wave & 1;       // 0..1 -> 64 rows of B (cols of C)
    const int lrow = lane & 15;
    const int lk = lane >> 4;      // 0..3
    const int rslot = (lk ^ ((lrow >> 1) & 3)) << 4;  // measured 0 conflicts (r5/r9)

    // XCD-aware bijective swizzle: 6144 = 8 * 768
    const int flat = blockIdx.x;
    const int sw = (flat & 7) * 768 + (flat >> 3);
    const int bm = sw / 96;  // 0..63
    const int bn = sw % 96;  // 0..95

    // staging: A-tile 128x64B = 512 16B-slots; thread t covers slots t and t+256.
    // linear LDS dest; global k-slot permuted by the reader's involution
    // g = (t&3) ^ ((row>>1)&3); row = t>>2 (+64 for slot 2: same g since 64%8==0).
    const int g = (t & 3) ^ ((t >> 3) & 3);
    const size_t aoff0 = (size_t)(bm * 128 + (t >> 2)) * K_DIM + (size_t)g * 16;
    const size_t aoff1 = aoff0 + (size_t)64 * K_DIM;
    const size_t boff0 = (size_t)(bn * 128 + (t >> 2)) * K_DIM + (size_t)g * 16;
    const size_t boff1 = boff0 + (size_t)64 * K_DIM;

#define STAGE(sb, jt)                                                          \
    {                                                                          \
        gload_lds16(qa + aoff0 + (size_t)(jt) * 64, &lds[sb][0][t * 16]);      \
        gload_lds16(qa + aoff1 + (size_t)(jt) * 64, &lds[sb][0][t * 16 + 4096]); \
        gload_lds16(wq + boff0 + (size_t)(jt) * 64, &lds[sb][1][t * 16]);      \
        gload_lds16(wq + boff1 + (size_t)(jt) * 64, &lds[sb][1][t * 16 + 4096]); \
    }

#define SB0 __builtin_amdgcn_sched_barrier(0);
#define BAR __builtin_amdgcn_s_barrier();
#define WAIT_LGKM(n) asm volatile("s_waitcnt lgkmcnt(" #n ")" ::: "memory");
#define WAIT_VM(n) asm volatile("s_waitcnt vmcnt(" #n ")" ::: "memory");

    i32x4 acc[4][4] = {};
    i32x4 a[4], b[4];

    // prologue: stage tile 0
    STAGE(0, 0);

    for (int j = 0; j < KT; ++j) {
        const int cs = j & 1;
        const int ns = cs ^ 1;
        if (j + 1 < KT) {
            STAGE(ns, j + 1);   // 4 gload for tile j+1
            WAIT_VM(4);         // tile j's 4 loads landed; j+1's stay in flight
        } else {
            WAIT_VM(0);
        }
        SB0;
        BAR;  // all waves' tile-j slices in LDS
        SB0;
#pragma unroll
        for (int nf = 0; nf < 4; ++nf)
            b[nf] = *(const i32x4*)&lds[cs][1][(wn * 64 + nf * 16 + lrow) * 64 + rslot];
#pragma unroll
        for (int mf = 0; mf < 4; ++mf)
            a[mf] = *(const i32x4*)&lds[cs][0][(wm * 64 + mf * 16 + lrow) * 64 + rslot];
        WAIT_LGKM(0);
        SB0;
        BAR;  // all waves' reads of slot cs retired -> next iter may overwrite
        SB0;
        __builtin_amdgcn_s_setprio(1);
#pragma unroll
        for (int mf = 0; mf < 4; ++mf)
#pragma unroll
            for (int nf = 0; nf < 4; ++nf)
                acc[mf][nf] = __builtin_amdgcn_mfma_i32_16x16x64_i8(
                    a[mf], b[nf], acc[mf][nf], 0, 0, 0);
        __builtin_amdgcn_s_setprio(0);
        SB0;
    }

    // epilogue: C/D layout col = lane&15, row = (lane>>4)*4 + jj
    const int r0 = bm * 128 + wm * 64;
    const int c0 = bn * 128 + wn * 64;
    float asc[4][4];
#pragma unroll
    for (int m = 0; m < 4; ++m)
#pragma unroll
        for (int jj = 0; jj < 4; ++jj)
            asc[m][jj] = ascale[r0 + m * 16 + lk * 4 + jj];
#pragma unroll
    for (int n = 0; n < 4; ++n) {
        const int col = c0 + n * 16 + lrow;
        const float wsc = wscale[col];
        const float bb = bias[col];
#pragma unroll
        for (int m = 0; m < 4; ++m) {
#pragma unroll
            for (int jj = 0; jj < 4; ++jj) {
                const int row = r0 + m * 16 + lk * 4 + jj;
                out[(size_t)row * N_DIM + col] = (float)acc[m][n][jj] * asc[m][jj] * wsc + bb;
            }
        }
    }
}

extern "C" void kernel_launch(void* const* d_in, const int* in_sizes, int n_in,
                              void* d_out, int out_size, void* d_ws, size_t ws_size,
                              hipStream_t stream) {
    const float* x = (const float*)d_in[0];
    const int* w32 = (const int*)d_in[1];  // int8 weights arrive as int32
    const float* wscale = (const float*)d_in[2];
    const float* bias = (const float*)d_in[3];
    float* out = (float*)d_out;

    int8_t* qa = (int8_t*)d_ws;                                     // M*K int8
    float* ascale = (float*)((char*)d_ws + (size_t)M_DIM * K_DIM);  // M f32
    int8_t* wq = (int8_t*)((char*)d_ws + (size_t)M_DIM * K_DIM +
                           (size_t)M_DIM * sizeof(float));          // N*K int8

    quant_pack<<<M_DIM + 2048, 256, 0, stream>>>(x, w32, qa, ascale, wq);
    gemm_i8<<<6144, 256, 0, stream>>>(qa, wq, ascale, wscale, bias, out);
}

// Round 15
// 506.840 us; speedup vs baseline: 1.3099x; 1.3099x over previous
//
#include <hip/hip_runtime.h>
#include <cstdint>

#define M_DIM 8192
#define K_DIM 4096
#define N_DIM 12288
#define KT 32  // K-tiles of BK=128 int8 (128 B per row)

using i32x4 = __attribute__((ext_vector_type(4))) int;

__device__ inline void gload_lds16(const void* g, void* l) {
    __builtin_amdgcn_global_load_lds(
        (const __attribute__((address_space(1))) void*)g,
        (__attribute__((address_space(3))) void*)l,
        16, 0, 0);
}

// ---- fused prologue: blocks 0..2047 quantize 4 rows each (1 wave/row, no LDS,
// ---- no barrier, coalesced 64B/lane loads + dwordx4 stores); blocks 2048+ pack W.
__global__ __launch_bounds__(256) void quant_pack(const float* __restrict__ x,
                                                  const int* __restrict__ w32,
                                                  int8_t* __restrict__ qa,
                                                  float* __restrict__ ascale,
                                                  int8_t* __restrict__ wq) {
    const int t = threadIdx.x;
    if (blockIdx.x < 2048) {
        const int lane = t & 63;
        const int row = blockIdx.x * 4 + (t >> 6);
        const float4* xr = (const float4*)(x + (size_t)row * K_DIM);
        float4 v[4][4];
        float amax = 0.0f;
#pragma unroll
        for (int cc = 0; cc < 4; ++cc) {
            const float4* base = xr + cc * 256 + lane * 4;  // 64 B contiguous/lane
#pragma unroll
            for (int c = 0; c < 4; ++c) {
                v[cc][c] = base[c];
                amax = fmaxf(amax,
                             fmaxf(fmaxf(fabsf(v[cc][c].x), fabsf(v[cc][c].y)),
                                   fmaxf(fabsf(v[cc][c].z), fabsf(v[cc][c].w))));
            }
        }
#pragma unroll
        for (int off = 32; off > 0; off >>= 1)
            amax = fmaxf(amax, __shfl_xor(amax, off));
        const float sc = amax * (1.0f / 127.0f);
        const float inv = (amax > 0.0f) ? (127.0f / amax) : 0.0f;
        if (lane == 0) ascale[row] = sc;

        int* q32 = (int*)(qa + (size_t)row * K_DIM);
#pragma unroll
        for (int cc = 0; cc < 4; ++cc) {
            int p[4];
#pragma unroll
            for (int c = 0; c < 4; ++c) {
                int q0 = (int)rintf(v[cc][c].x * inv);
                int q1 = (int)rintf(v[cc][c].y * inv);
                int q2 = (int)rintf(v[cc][c].z * inv);
                int q3 = (int)rintf(v[cc][c].w * inv);
                q0 = min(127, max(-128, q0));
                q1 = min(127, max(-128, q1));
                q2 = min(127, max(-128, q2));
                q3 = min(127, max(-128, q3));
                p[c] = (q0 & 255) | ((q1 & 255) << 8) | ((q2 & 255) << 16) | (q3 << 24);
            }
            int4 o = make_int4(p[0], p[1], p[2], p[3]);
            *(int4*)(q32 + cc * 256 + lane * 4) = o;  // matches load indexing
        }
    } else {
        const int pb = blockIdx.x - 2048;  // 0..2047
        const size_t total4 = (size_t)N_DIM * K_DIM / 4;
        const size_t stride = (size_t)2048 * 256;
        int* out32 = (int*)wq;
        for (size_t i = (size_t)pb * 256 + t; i < total4; i += stride) {
            const int4 v = ((const int4*)w32)[i];
            out32[i] = (v.x & 255) | ((v.y & 255) << 8) | ((v.z & 255) << 16) | (v.w << 24);
        }
    }
}

// ---- int8 GEMM: 256x256, BK=128, dbuf LDS, 4-phase/K-tile (r7 verbatim: best, 410us)
__global__ __launch_bounds__(512, 2) void gemm_i8(const int8_t* __restrict__ qa,
                                                  const int8_t* __restrict__ wq,
                                                  const float* __restrict__ ascale,
                                                  const float* __restrict__ wscale,
                                                  const float* __restrict__ bias,
                                                  float* __restrict__ out) {
    __shared__ int8_t lds[2][2][32768];  // [slot][A,B][256 rows x 128 B] = 128 KiB

    const int t = threadIdx.x;
    const int lane = t & 63;
    const int wave = t >> 6;       // 0..7
    const int wm = wave >> 2;      // 0..1 -> 128 rows of A
    const int wn = wave & 3;       // 0..3 -> 64 rows of B (cols of C)
    const int lrow = lane & 15;
    const int lk = lane >> 4;      // 0..3 (16B sub-slot within 64B k-slice)
    const int sw7 = lrow & 7;      // read-side XOR swizzle

    // XCD-aware bijective swizzle: 1536 = 8 * 192
    const int flat = blockIdx.x;
    const int sw = (flat & 7) * 192 + (flat >> 3);
    const int bm = sw / 48;  // 0..31
    const int bn = sw % 48;  // 0..47

    // staging: linear LDS dest (slot c*8192 + t*16); GLOBAL k-slot g = sl ^ (row&7)
    // — same involution the reader applies (verified: 0 bank conflicts).
    const int srow = t >> 3;                 // 0..63
    const int g = (t & 7) ^ (srow & 7);      // row&7 invariant under +64c

#define STAGE_OP(ptr, sb, op, rowbase, jt)                                     \
    {                                                                          \
        _Pragma("unroll") for (int c = 0; c < 4; ++c)                          \
            gload_lds16(ptr + (size_t)((rowbase) + srow + 64 * c) * K_DIM +    \
                            (size_t)g * 16 + (size_t)(jt) * 128,               \
                        &lds[sb][op][c * 8192 + t * 16]);                      \
    }

#define READ_A(dst, LA, mh)                                                    \
    {                                                                          \
        _Pragma("unroll") for (int mf = 0; mf < 4; ++mf)                       \
            _Pragma("unroll") for (int ks = 0; ks < 2; ++ks)                   \
                dst[mf][ks] = *(const i32x4*)&LA[(wm * 128 + (mh)*64 +         \
                                                 mf * 16 + lrow) * 128 +       \
                                                ((((ks << 2) | lk) ^ sw7) << 4)]; \
    }
#define READ_B(dst, LB, nh)                                                    \
    {                                                                          \
        _Pragma("unroll") for (int nf = 0; nf < 2; ++nf)                       \
            _Pragma("unroll") for (int ks = 0; ks < 2; ++ks)                   \
                dst[nf][ks] = *(const i32x4*)&LB[(wn * 64 + (nh)*32 +          \
                                                 nf * 16 + lrow) * 128 +       \
                                                ((((ks << 2) | lk) ^ sw7) << 4)]; \
    }
#define MM(AH, BH, mh, nh)                                                     \
    {                                                                          \
        __builtin_amdgcn_s_setprio(1);                                         \
        _Pragma("unroll") for (int ks = 0; ks < 2; ++ks)                       \
            _Pragma("unroll") for (int mf = 0; mf < 4; ++mf)                   \
                _Pragma("unroll") for (int nf = 0; nf < 2; ++nf)               \
                    acc[(mh)*4 + mf][(nh)*2 + nf] =                            \
                        __builtin_amdgcn_mfma_i32_16x16x64_i8(                 \
                            AH[mf][ks], BH[nf][ks],                            \
                            acc[(mh)*4 + mf][(nh)*2 + nf], 0, 0, 0);           \
        __builtin_amdgcn_s_setprio(0);                                         \
    }
#define LGKM0_PIN                                                              \
    asm volatile("s_waitcnt lgkmcnt(0)" ::: "memory");                         \
    __builtin_amdgcn_sched_barrier(0);

    i32x4 acc[8][4] = {};
    i32x4 a0[4][2], a1[4][2], b0[2][2], b1[2][2];

    // prologue: stage tile 0 fully (8 loads/thread outstanding)
    STAGE_OP(qa, 0, 0, bm * 256, 0);
    STAGE_OP(wq, 0, 1, bn * 256, 0);

    for (int j = 0; j < KT; ++j) {
        const int cs = j & 1;
        const int ns = cs ^ 1;
        const int8_t* __restrict__ LA = lds[cs][0];
        const int8_t* __restrict__ LB = lds[cs][1];

        // ---- phase 0: stage A(j+1) | counted wait | barrier | read a0,b0 | MM(0,0)
        if (j + 1 < KT) {
            STAGE_OP(qa, ns, 0, bm * 256, j + 1);
            asm volatile("s_waitcnt vmcnt(4)" ::: "memory");  // tile j landed
        } else {
            asm volatile("s_waitcnt vmcnt(0)" ::: "memory");
        }
        __builtin_amdgcn_s_barrier();
        __builtin_amdgcn_sched_barrier(0);
        READ_A(a0, LA, 0);
        READ_B(b0, LB, 0);
        LGKM0_PIN;
        MM(a0, b0, 0, 0);

        // ---- phase 1: read b1 | stage B(j+1) | barrier | MM(a0,b1)
        READ_B(b1, LB, 1);
        if (j + 1 < KT) STAGE_OP(wq, ns, 1, bn * 256, j + 1);
        __builtin_amdgcn_s_barrier();
        LGKM0_PIN;
        MM(a0, b1, 0, 1);

        // ---- phase 2: read a1 | barrier | MM(a1,b1)
        READ_A(a1, LA, 1);
        __builtin_amdgcn_s_barrier();
        LGKM0_PIN;
        MM(a1, b1, 1, 1);

        // ---- phase 3: barrier | MM(a1,b0)  (b0, a1 already in regs)
        __builtin_amdgcn_s_barrier();
        __builtin_amdgcn_sched_barrier(0);
        MM(a1, b0, 1, 0);
    }

    // epilogue: C/D layout col = lane&15, row = (lane>>4)*4 + j
    const int r0 = bm * 256 + wm * 128;
    const int c0 = bn * 256 + wn * 64;
    float asc[8][4];
#pragma unroll
    for (int m = 0; m < 8; ++m)
#pragma unroll
        for (int jj = 0; jj < 4; ++jj)
            asc[m][jj] = ascale[r0 + m * 16 + lk * 4 + jj];
#pragma unroll
    for (int n = 0; n < 4; ++n) {
        const int col = c0 + n * 16 + lrow;
        const float wsc = wscale[col];
        const float bb = bias[col];
#pragma unroll
        for (int m = 0; m < 8; ++m) {
#pragma unroll
            for (int jj = 0; jj < 4; ++jj) {
                const int row = r0 + m * 16 + lk * 4 + jj;
                out[(size_t)row * N_DIM + col] = (float)acc[m][n][jj] * asc[m][jj] * wsc + bb;
            }
        }
    }
}

extern "C" void kernel_launch(void* const* d_in, const int* in_sizes, int n_in,
                              void* d_out, int out_size, void* d_ws, size_t ws_size,
                              hipStream_t stream) {
    const float* x = (const float*)d_in[0];
    const int* w32 = (const int*)d_in[1];  // int8 weights arrive as int32
    const float* wscale = (const float*)d_in[2];
    const float* bias = (const float*)d_in[3];
    float* out = (float*)d_out;

    int8_t* qa = (int8_t*)d_ws;                                     // M*K int8
    float* ascale = (float*)((char*)d_ws + (size_t)M_DIM * K_DIM);  // M f32
    int8_t* wq = (int8_t*)((char*)d_ws + (size_t)M_DIM * K_DIM +
                           (size_t)M_DIM * sizeof(float));          // N*K int8

    quant_pack<<<4096, 256, 0, stream>>>(x, w32, qa, ascale, wq);
    gemm_i8<<<1536, 512, 0, stream>>>(qa, wq, ascale, wscale, bias, out);
}